// Round 10
// baseline (337.085 us; speedup 1.0000x reference)
//
#include <hip/hip_runtime.h>
#include <hip/hip_bf16.h>
#include <cstdint>
#include <cstddef>

typedef __bf16 bf16_t;
typedef bf16_t bf16x8 __attribute__((ext_vector_type(8)));
typedef bf16_t bf16x4 __attribute__((ext_vector_type(4)));
typedef float f32x4 __attribute__((ext_vector_type(4)));

#define NB 8
#define NT 1024
#define NC 1024
#define NH 16
#define ND 64
#define NTP 64

// ---------------- fused cast fp32 -> bf16 for x and prefix (one launch) ----------------
__global__ __launch_bounds__(256) void k_cast2(const float* __restrict__ a, bf16_t* __restrict__ da,
                                               int n4a,
                                               const float* __restrict__ b2, bf16_t* __restrict__ db,
                                               int n4b) {
    int i = blockIdx.x * 256 + threadIdx.x;
    if (i < n4a) {
        float4 f = ((const float4*)a)[i];
        bf16x4 o;
        o[0] = (bf16_t)f.x; o[1] = (bf16_t)f.y; o[2] = (bf16_t)f.z; o[3] = (bf16_t)f.w;
        ((bf16x4*)da)[i] = o;
    } else {
        int j = i - n4a;
        if (j < n4b) {
            float4 f = ((const float4*)b2)[j];
            bf16x4 o;
            o[0] = (bf16_t)f.x; o[1] = (bf16_t)f.y; o[2] = (bf16_t)f.z; o[3] = (bf16_t)f.w;
            ((bf16x4*)db)[j] = o;
        }
    }
}

// ------- all 3 weight transposes (K,N) fp32 -> (N,K) bf16 in ONE launch -------
__global__ __launch_bounds__(256) void k_transpose3(const float* __restrict__ s0, bf16_t* __restrict__ d0,
                                                    const float* __restrict__ s1, bf16_t* __restrict__ d1,
                                                    const float* __restrict__ s2, bf16_t* __restrict__ d2) {
    __shared__ float tile[32][33];
    const int z = blockIdx.z;
    const float* src = (z == 0) ? s0 : (z == 1) ? s1 : s2;
    bf16_t* dst = (z == 0) ? d0 : (z == 1) ? d1 : d2;
    const int N = (z == 2) ? NC : 3 * NC;
    const int K = NC;
    if (z == 2 && blockIdx.x >= 32) return;
    int nt = blockIdx.x, kt = blockIdx.y;
    int tx = threadIdx.x & 31;
    int ty = threadIdx.x >> 5;  // 0..7
#pragma unroll
    for (int i = 0; i < 4; i++) {
        int r = ty + i * 8;
        tile[r][tx] = src[(size_t)(kt * 32 + r) * N + nt * 32 + tx];
    }
    __syncthreads();
#pragma unroll
    for (int i = 0; i < 4; i++) {
        int r = ty + i * 8;
        dst[(size_t)(nt * 32 + r) * K + kt * 32 + tx] = (bf16_t)tile[tx][r];
    }
}

// =============== 256x256 8-phase counted-vmcnt GEMM (qkv+pqkv merged) ===============
// Faithful m198-style port (no LDS swizzle). BM=BN=256, BK=64, 8 waves (2M x 4N),
// per-wave output 128x64. LDS [2 buf][2 half][128][64] per operand = 128 KB.
// Per K-tile kt (4 phases c0..c3):
//   c0: vmcnt(4) [vmcnt(0) last tile] -> barrier -> stage A-half0(kt+1) ->
//       ds_read 8 B-frags + 4 A-frags -> lgkmcnt(0) -> 16 MFMA
//   c1: barrier -> stage A-half1(kt+1) -> 4 A-frags -> lgkm -> 16 MFMA
//   c2: barrier -> stage B-half0(kt+2) -> 4 A-frags -> lgkm -> 16 MFMA
//   c3: barrier -> stage B-half1(kt+2) -> 4 A-frags -> lgkm -> 16 MFMA
// FIFO proof: queue entering c0 = [B(kt)x4, A(kt)x4, B(kt+1)x4]; vmcnt(4)
// completes B(kt)+A(kt), leaves B(kt+1). Overwrite safety: a stage at phase p
// only overwrites data last ds_read at p-1, drained by each wave's lgkmcnt(0)
// before its MFMA and joined by p's barrier. Raw s_barrier (NOT __syncthreads:
// that drains vmcnt(0) and kills the pipeline).

#define STG8(ldsptr, gptr)                                                                     \
    {                                                                                          \
        _Pragma("unroll") for (int i_ = 0; i_ < 2; i_++) {                                     \
            const bf16_t* s_ =                                                                 \
                (gptr) + (size_t)((wave * 2 + i_) * 8 + (lane >> 3)) * 1024 + (lane & 7) * 8;  \
            __builtin_amdgcn_global_load_lds(                                                  \
                (const __attribute__((address_space(1))) void*)s_,                             \
                (__attribute__((address_space(3))) void*)((ldsptr) + (wave * 2 + i_) * 512),   \
                16, 0, 0);                                                                     \
        }                                                                                      \
    }

#define LDA8(mi_, kk_) (*(const bf16x8*)(&As[abase + ((mi_) * 16 + l15) * 64 + (kk_) * 32 + quad * 8]))
#define LDB8(nj_, kk_) (*(const bf16x8*)(&Bs[bbase + (bloc + (nj_) * 16 + l15) * 64 + (kk_) * 32 + quad * 8]))

#define PBAR()                               \
    __builtin_amdgcn_sched_barrier(0);       \
    __builtin_amdgcn_s_barrier();            \
    __builtin_amdgcn_sched_barrier(0);

#define LGKM0()                                        \
    asm volatile("s_waitcnt lgkmcnt(0)" ::: "memory"); \
    __builtin_amdgcn_sched_barrier(0);

#define MFMAPH(c_)                                                                  \
    __builtin_amdgcn_s_setprio(1);                                                  \
    _Pragma("unroll") for (int m_ = 0; m_ < 2; m_++)                                \
        _Pragma("unroll") for (int n_ = 0; n_ < 4; n_++) {                          \
            acc[(c_) * 2 + m_][n_] = __builtin_amdgcn_mfma_f32_16x16x32_bf16(       \
                af[m_ * 2 + 0], bfr[n_ * 2 + 0], acc[(c_) * 2 + m_][n_], 0, 0, 0);  \
            acc[(c_) * 2 + m_][n_] = __builtin_amdgcn_mfma_f32_16x16x32_bf16(       \
                af[m_ * 2 + 1], bfr[n_ * 2 + 1], acc[(c_) * 2 + m_][n_], 0, 0, 0);  \
        }                                                                           \
    __builtin_amdgcn_s_setprio(0);

#define AFRD(base_)                                        \
    af[0] = LDA8((base_) + 0, 0); af[1] = LDA8((base_) + 0, 1); \
    af[2] = LDA8((base_) + 1, 0); af[3] = LDA8((base_) + 1, 1);

__global__ __launch_bounds__(512, 2) void k_gemm8(const bf16_t* __restrict__ xb,
                                                  const bf16_t* __restrict__ pb,
                                                  const bf16_t* __restrict__ wTa,
                                                  const bf16_t* __restrict__ wTp,
                                                  const float* __restrict__ b_attn,
                                                  const float* __restrict__ b_prefix,
                                                  bf16_t* __restrict__ qkv,
                                                  bf16_t* __restrict__ pqkv) {
    const int bx = blockIdx.x;   // 0..11
    const int byw = blockIdx.y;  // 0..33 (32,33 = prefix rows)
    const bool pre = (byw >= 32);
    const bf16_t* A = pre ? pb : xb;
    const bf16_t* BT = pre ? wTp : wTa;
    const float* bias = pre ? b_prefix : b_attn;
    bf16_t* Cout = pre ? pqkv : qkv;
    const int tsh = pre ? 6 : 10;
    const size_t rowA0 = (size_t)(pre ? (byw - 32) : byw) * 256;
    const size_t colB0 = (size_t)bx * 256;
    const int N = 3 * NC;
    const int NKT = 16;  // K=1024 / 64

    __shared__ bf16_t As[2 * 2 * 128 * 64];  // [buf][half][128][64] = 64 KB
    __shared__ bf16_t Bs[2 * 2 * 128 * 64];  // 64 KB

    const int tid = threadIdx.x;
    const int lane = tid & 63;
    const int wave = tid >> 6;       // 0..7
    const int quad = lane >> 4;
    const int l15 = lane & 15;
    const int wm = (wave >> 2) * 128;  // 0 / 128
    const int wn = (wave & 3) * 64;    // 0..192
    const int ah = wm >> 7;            // A half this wave reads
    const int bh = wn >> 7;            // B half this wave reads
    const int bloc = wn & 127;         // local row in B half

    const f32x4 fz = {0.f, 0.f, 0.f, 0.f};
    f32x4 acc[8][4];
#pragma unroll
    for (int i = 0; i < 8; i++)
#pragma unroll
        for (int j = 0; j < 4; j++) acc[i][j] = fz;
    bf16x8 af[4], bfr[8];

    // ---- prologue stages (FIFO order defines all vmcnt math): B0(0) B1(0) A0(0) A1(0) B0(1) B1(1)
    STG8(Bs + 0 * 8192, BT + colB0 * 1024)
    STG8(Bs + 1 * 8192, BT + (colB0 + 128) * 1024)
    STG8(As + 0 * 8192, A + rowA0 * 1024)
    STG8(As + 1 * 8192, A + (rowA0 + 128) * 1024)
    STG8(Bs + 2 * 8192, BT + colB0 * 1024 + 64)
    STG8(Bs + 3 * 8192, BT + (colB0 + 128) * 1024 + 64)

    for (int kt = 0; kt < NKT; kt++) {
        const int cur = kt & 1, nxt = cur ^ 1;
        const int abase = (cur * 2 + ah) * 8192;
        const int bbase = (cur * 2 + bh) * 8192;
        // ---- c0 ----
        if (kt < NKT - 1) { asm volatile("s_waitcnt vmcnt(4)" ::: "memory"); }
        else              { asm volatile("s_waitcnt vmcnt(0)" ::: "memory"); }
        PBAR();
        if (kt < NKT - 1) STG8(As + (nxt * 2 + 0) * 8192, A + rowA0 * 1024 + (kt + 1) * 64)
#pragma unroll
        for (int n_ = 0; n_ < 4; n_++) { bfr[n_ * 2] = LDB8(n_, 0); bfr[n_ * 2 + 1] = LDB8(n_, 1); }
        AFRD(0)
        LGKM0(); MFMAPH(0)
        // ---- c1 ----
        PBAR();
        if (kt < NKT - 1) STG8(As + (nxt * 2 + 1) * 8192, A + (rowA0 + 128) * 1024 + (kt + 1) * 64)
        AFRD(2)
        LGKM0(); MFMAPH(1)
        // ---- c2 ----
        PBAR();
        if (kt < NKT - 2) STG8(Bs + (cur * 2 + 0) * 8192, BT + colB0 * 1024 + (kt + 2) * 64)
        AFRD(4)
        LGKM0(); MFMAPH(2)
        // ---- c3 ----
        PBAR();
        if (kt < NKT - 2) STG8(Bs + (cur * 2 + 1) * 8192, BT + (colB0 + 128) * 1024 + (kt + 2) * 64)
        AFRD(6)
        LGKM0(); MFMAPH(3)
    }

    // ---- epilogue: qkv-mode C write (V third -> transposed tile remap) ----
    const bool vpath = (colB0 >= (size_t)(2 * NC));
#pragma unroll
    for (int i = 0; i < 8; i++) {
        size_t row = rowA0 + wm + i * 16 + quad * 4;
#pragma unroll
        for (int j = 0; j < 4; j++) {
            int col = (int)colB0 + wn + j * 16 + l15;
            float bv = bias[col];
            if (vpath) {
                int hh = (col - 2 * NC) >> 6;
                int dd = col & 63;
                int bb = (int)(row >> tsh);
                int tt = (int)row & ((1 << tsh) - 1);
                int tileBase = (bb * NH + hh) * (1 << (tsh - 6)) + (tt >> 6);
                size_t chunkrow = (size_t)tileBase * 4 + (dd >> 4);
                size_t addr = chunkrow * (size_t)N + 2 * NC + (dd & 15) * 64 + (tt & 63);
                bf16x4 vv;
#pragma unroll
                for (int r = 0; r < 4; r++) vv[r] = (bf16_t)(acc[i][j][r] + bv);
                *(bf16x4*)(Cout + addr) = vv;
            } else {
#pragma unroll
                for (int r = 0; r < 4; r++) {
                    float v = acc[i][j][r] + bv;
                    Cout[(row + r) * (size_t)N + col] = (bf16_t)v;
                }
            }
        }
    }
}

// ---------------- proj GEMM: out(f32) = yb @ wTpr + b_proj (XCD-swizzled) ----------------
__global__ __launch_bounds__(256) void k_gemm_proj(const bf16_t* __restrict__ A,
                                                   const bf16_t* __restrict__ BT,
                                                   const float* __restrict__ bias,
                                                   float* __restrict__ Cout,
                                                   int M, int N, int K) {
    const int nwg = gridDim.x * gridDim.y;
    const int flat = blockIdx.y * gridDim.x + blockIdx.x;
    const int wgid = (flat & 7) * (nwg >> 3) + (flat >> 3);
    const int bx = wgid % gridDim.x;
    const int byw = wgid / gridDim.x;
    const size_t rowA0 = (size_t)byw * 128;
    const size_t colB0 = (size_t)bx * 128;

    __shared__ bf16_t As[128 * 72];
    __shared__ bf16_t Bs[128 * 72];
    const int tid = threadIdx.x;
    const int lane = tid & 63;
    const int wave = tid >> 6;
    const int quad = lane >> 4;
    const int l15 = lane & 15;
    const int wm = (wave >> 1) * 64;
    const int wn = (wave & 1) * 64;

    const f32x4 fz = {0.f, 0.f, 0.f, 0.f};
    f32x4 acc[4][4];
#pragma unroll
    for (int i = 0; i < 4; i++)
#pragma unroll
        for (int j = 0; j < 4; j++) acc[i][j] = fz;

    for (int k0 = 0; k0 < K; k0 += 64) {
        __syncthreads();
#pragma unroll
        for (int i = 0; i < 4; i++) {
            int c = tid + i * 256;
            int r = c >> 3;
            int kc = (c & 7) * 8;
            uint4 av = *(const uint4*)(A + (rowA0 + r) * (size_t)K + k0 + kc);
            *(uint4*)(&As[r * 72 + kc]) = av;
            uint4 bv = *(const uint4*)(BT + (colB0 + r) * (size_t)K + k0 + kc);
            *(uint4*)(&Bs[r * 72 + kc]) = bv;
        }
        __syncthreads();
#pragma unroll
        for (int kk = 0; kk < 2; kk++) {
            bf16x8 af[4], bfr[4];
#pragma unroll
            for (int i = 0; i < 4; i++)
                af[i] = *(const bf16x8*)(&As[(wm + i * 16 + l15) * 72 + kk * 32 + quad * 8]);
#pragma unroll
            for (int j = 0; j < 4; j++)
                bfr[j] = *(const bf16x8*)(&Bs[(wn + j * 16 + l15) * 72 + kk * 32 + quad * 8]);
#pragma unroll
            for (int i = 0; i < 4; i++)
#pragma unroll
                for (int j = 0; j < 4; j++)
                    acc[i][j] = __builtin_amdgcn_mfma_f32_16x16x32_bf16(af[i], bfr[j], acc[i][j], 0, 0, 0);
        }
    }
#pragma unroll
    for (int i = 0; i < 4; i++) {
        size_t row = rowA0 + wm + i * 16 + quad * 4;
#pragma unroll
        for (int j = 0; j < 4; j++) {
            int col = (int)colB0 + wn + j * 16 + l15;
            float bv = bias[col];
#pragma unroll
            for (int r = 0; r < 4; r++)
                Cout[(row + r) * (size_t)N + col] = acc[i][j][r] + bv;
        }
    }
}

// ---------------- fused dual-softmax causal attention (R8, unchanged) ------------
#define LOADREGS(KB, VCB)                                                            \
    rk0 = *(const uint4*)((KB) + (size_t)(tid >> 3) * 3072 + (tid & 7) * 8);         \
    rv0 = *(const uint4*)((VCB) + (size_t)(tid >> 7) * 3072 + (tid & 127) * 8);

#define STAGE(KS, VS)                                                \
    *(uint4*)(&(KS)[(tid >> 3) * 72 + (tid & 7) * 8]) = rk0;         \
    *(uint4*)(&(VS)[(tid >> 3) * 72 + (tid & 7) * 8]) = rv0;

#define QK(KS, Sj, j)                                                                  \
    Sj = __builtin_amdgcn_mfma_f32_16x16x32_bf16(                                      \
        aq0, *(const bf16x8*)(&(KS)[((j) * 16 + l15) * 72 + quad * 8]), Sj, 0, 0, 0);  \
    Sj = __builtin_amdgcn_mfma_f32_16x16x32_bf16(                                      \
        aq1, *(const bf16x8*)(&(KS)[((j) * 16 + l15) * 72 + 32 + quad * 8]), Sj, 0, 0, 0);

#define EXPJ(Sj, j, BL, LACC)                                           \
    {                                                                   \
        const int n_ = (j) * 16 + l15;                                  \
        _Pragma("unroll") for (int r_ = 0; r_ < 4; r_++) {              \
            float p_ = __expf(Sj[r_] * scale);                          \
            if (n_ > (BL) + r_) p_ = 0.f;                               \
            Sj[r_] = p_;                                                \
            LACC[r_] += p_;                                             \
        }                                                               \
    }

#define PSTORE(Sj, j)                                                   \
    _Pragma("unroll") for (int r_ = 0; r_ < 4; r_++)                    \
        P[(quad * 4 + r_) * 72 + (j) * 16 + l15] = (bf16_t)Sj[r_];

#define PV(VS, Oj, j)                                                                  \
    Oj = __builtin_amdgcn_mfma_f32_16x16x32_bf16(                                      \
        ap0, *(const bf16x8*)(&(VS)[((j) * 16 + l15) * 72 + quad * 8]), Oj, 0, 0, 0);  \
    Oj = __builtin_amdgcn_mfma_f32_16x16x32_bf16(                                      \
        ap1, *(const bf16x8*)(&(VS)[((j) * 16 + l15) * 72 + 32 + quad * 8]), Oj, 0, 0, 0);

#define PROC(KS, VS, BL, LACC, O0, O1, O2, O3)                          \
    {                                                                   \
        f32x4 S0 = fz, S1 = fz, S2 = fz, S3 = fz;                       \
        __builtin_amdgcn_s_setprio(1);                                  \
        QK(KS, S0, 0) QK(KS, S1, 1) QK(KS, S2, 2) QK(KS, S3, 3)         \
        __builtin_amdgcn_s_setprio(0);                                  \
        EXPJ(S0, 0, BL, LACC) EXPJ(S1, 1, BL, LACC)                     \
        EXPJ(S2, 2, BL, LACC) EXPJ(S3, 3, BL, LACC)                     \
        PSTORE(S0, 0) PSTORE(S1, 1) PSTORE(S2, 2) PSTORE(S3, 3)         \
        __builtin_amdgcn_s_waitcnt(0xc07f); /* lgkmcnt(0) */            \
        __builtin_amdgcn_wave_barrier();                                \
        bf16x8 ap0 = *(const bf16x8*)(&P[l15 * 72 + quad * 8]);         \
        bf16x8 ap1 = *(const bf16x8*)(&P[l15 * 72 + 32 + quad * 8]);    \
        __builtin_amdgcn_s_setprio(1);                                  \
        PV(VS, O0, 0) PV(VS, O1, 1) PV(VS, O2, 2) PV(VS, O3, 3)         \
        __builtin_amdgcn_s_setprio(0);                                  \
    }

#define STORE_O(Oj, Pj, j)                                                            \
    _Pragma("unroll") for (int r_ = 0; r_ < 4; r_++) {                                \
        float v_ = Oj[r_] * lmv[r_] + Pj[r_] * lpv[r_];                               \
        y[(qrow0 + quad * 4 + r_) * NC + h * 64 + (j) * 16 + l15] = (bf16_t)v_;       \
    }

__global__ __launch_bounds__(512, 2) void k_attn11(const bf16_t* __restrict__ qkv,
                                                   const bf16_t* __restrict__ pqkv,
                                                   bf16_t* __restrict__ y) {
    const int flat = (int)blockIdx.x + 8 * ((int)blockIdx.y + 16 * (int)blockIdx.z);
    const int wgid = (flat & 7) * 128 + (flat >> 3);
    const int qt = (NT / 128 - 1) - (wgid & 7);
    const int h = (wgid >> 3) & 15;
    const int b = wgid >> 7;
    const int TMAX = 2 * qt + 1;  // last main tile index

    __shared__ bf16_t Ks0[64 * 72], Ks1[64 * 72];
    __shared__ bf16_t Vs0[64 * 72], Vs1[64 * 72];
    __shared__ bf16_t Ps[8][16 * 72];

    const int tid = threadIdx.x;
    const int lane = tid & 63;
    const int wave = tid >> 6;       // 0..7
    const int quad = lane >> 4;
    const int l15 = lane & 15;
    const float scale = 0.125f;      // 1/sqrt(64)

    const size_t qrow0 = (size_t)b * NT + (size_t)qt * 128 + wave * 16;
    const int qoff = qt * 128 + wave * 16 + quad * 4;
    bf16_t* P = Ps[wave];

    const bf16_t* Kmain = qkv + (size_t)(b * NT) * 3072 + NC + h * 64;
    const bf16_t* Vmain = qkv + (size_t)(b * NH + h) * 16 * 4 * 3072 + 2 * NC;
    const bf16_t* Vpre  = pqkv + (size_t)(b * NH + h) * 4 * 3072 + 2 * NC;

    bf16x8 aq0 = *(const bf16x8*)(qkv + (qrow0 + l15) * 3072 + h * 64 + quad * 8);
    bf16x8 aq1 = *(const bf16x8*)(qkv + (qrow0 + l15) * 3072 + h * 64 + 32 + quad * 8);

    const f32x4 fz = {0.f, 0.f, 0.f, 0.f};
    f32x4 Om0 = fz, Om1 = fz, Om2 = fz, Om3 = fz;
    f32x4 Op0 = fz, Op1 = fz, Op2 = fz, Op3 = fz;
    f32x4 Lm = fz, Lp = fz;
    uint4 rk0, rv0;

    LOADREGS(pqkv + (size_t)(b * NTP) * 3072 + NC + h * 64, Vpre)
    STAGE(Ks0, Vs0)
    LOADREGS(Kmain, Vmain)
    __syncthreads();
    PROC(Ks0, Vs0, qoff, Lp, Op0, Op1, Op2, Op3)
    STAGE(Ks1, Vs1)
    LOADREGS(Kmain + (size_t)64 * 3072, Vmain + 4 * 3072)

    for (int t = 0; t <= TMAX; t++) {
        __syncthreads();
        bf16_t* KSc = (t & 1) ? Ks0 : Ks1;
        bf16_t* VSc = (t & 1) ? Vs0 : Vs1;
        if (t < TMAX) {
            bf16_t* KSn = (t & 1) ? Ks1 : Ks0;
            bf16_t* VSn = (t & 1) ? Vs1 : Vs0;
            STAGE(KSn, VSn)
        }
        if (t + 1 < TMAX) {
            LOADREGS(Kmain + ((size_t)(t + 2) * 64) * 3072, Vmain + (size_t)(t + 2) * 4 * 3072)
        }
        PROC(KSc, VSc, qoff - t * 64, Lm, Om0, Om1, Om2, Om3)
    }

    f32x4 lmv, lpv;
#pragma unroll
    for (int r = 0; r < 4; r++) {
        float vm = Lm[r], vpr = Lp[r];
#pragma unroll
        for (int off = 1; off < 16; off <<= 1) {
            vm += __shfl_xor(vm, off, 64);
            vpr += __shfl_xor(vpr, off, 64);
        }
        lmv[r] = 1.0f / vm;
        lpv[r] = 1.0f / vpr;
    }

    STORE_O(Om0, Op0, 0) STORE_O(Om1, Op1, 1) STORE_O(Om2, Op2, 2) STORE_O(Om3, Op3, 3)
}

// ---------------- launch ----------------
extern "C" void kernel_launch(void* const* d_in, const int* in_sizes, int n_in,
                              void* d_out, int out_size, void* d_ws, size_t ws_size,
                              hipStream_t stream) {
    (void)in_sizes; (void)n_in; (void)out_size; (void)ws_size;
    const float* x        = (const float*)d_in[0];
    const float* prefix   = (const float*)d_in[1];
    const float* w_attn   = (const float*)d_in[2];
    const float* b_attn   = (const float*)d_in[3];
    const float* w_prefix = (const float*)d_in[4];
    const float* b_prefix = (const float*)d_in[5];
    const float* w_proj   = (const float*)d_in[6];
    const float* b_proj   = (const float*)d_in[7];
    float* out = (float*)d_out;

    char* p = (char*)d_ws;
    auto carve = [&](size_t bytes) {
        char* q = p;
        p += (bytes + 255) & ~(size_t)255;
        return q;
    };
    bf16_t* xb   = (bf16_t*)carve((size_t)NB * NT * NC * 2);        // 16 MB
    bf16_t* pb   = (bf16_t*)carve((size_t)NB * NTP * NC * 2);       // 1 MB
    bf16_t* wTa  = (bf16_t*)carve((size_t)3 * NC * NC * 2);         // 6 MB
    bf16_t* wTp  = (bf16_t*)carve((size_t)3 * NC * NC * 2);         // 6 MB
    bf16_t* wTpr = (bf16_t*)carve((size_t)NC * NC * 2);             // 2 MB
    bf16_t* qkv  = (bf16_t*)carve((size_t)NB * NT * 3 * NC * 2);    // 48 MB (V third = tiled V)
    bf16_t* pqkv = (bf16_t*)carve((size_t)NB * NTP * 3 * NC * 2);   // 3 MB (V third = tiled V)
    bf16_t* yb   = (bf16_t*)carve((size_t)NB * NT * NC * 2);        // 16 MB

    const int n4a = NB * NT * NC / 4, n4b = NB * NTP * NC / 4;
    k_cast2<<<(n4a + n4b + 255) / 256, 256, 0, stream>>>(x, xb, n4a, prefix, pb, n4b);
    k_transpose3<<<dim3(3 * NC / 32, NC / 32, 3), 256, 0, stream>>>(w_attn, wTa, w_prefix, wTp,
                                                                    w_proj, wTpr);
    // merged qkv + pqkv GEMM (8-phase 256^2; V thirds -> transposed tile layout)
    k_gemm8<<<dim3(12, 34), 512, 0, stream>>>(xb, pb, wTa, wTp, b_attn, b_prefix, qkv, pqkv);
    // attention (QBLK=128, 8 waves, XCD-swizzled)
    k_attn11<<<dim3(NT / 128, NH, NB), 512, 0, stream>>>(qkv, pqkv, yb);
    // out = y @ w_proj + b_proj (fp32 out, XCD-swizzled)
    k_gemm_proj<<<dim3(NC / 128, NB * NT / 128), 256, 0, stream>>>(
        yb, wTpr, b_proj, out, NB * NT, NC, NC);
}